// Round 1
// baseline (1573.070 us; speedup 1.0000x reference)
//
#include <hip/hip_runtime.h>
#include <cstdint>
#include <cstddef>

typedef unsigned short u16;
typedef __attribute__((ext_vector_type(8))) short short8;   // 8 x bf16 bits (4 VGPRs)
typedef __attribute__((ext_vector_type(4))) float f32x4;

#define MFMA_BF16(a, b, c) __builtin_amdgcn_mfma_f32_16x16x32_bf16((a), (b), (c), 0, 0, 0)

__device__ __forceinline__ u16 f2bf(float f) {
  union { float f; unsigned u; } v; v.f = f;
  unsigned r = v.u + 0x7FFFu + ((v.u >> 16) & 1u);  // RNE
  return (u16)(r >> 16);
}

// B=4, S=2048, D=1024, H=16, DK=64
// ---------------------------------------------------------------------------
// fp32 -> bf16 convert (n multiple of 8)
// ---------------------------------------------------------------------------
__global__ __launch_bounds__(256) void cvt_f32_bf16(const float* __restrict__ src,
                                                    u16* __restrict__ dst, int n) {
  int i = (blockIdx.x * 256 + threadIdx.x) * 8;
  if (i >= n) return;
  f32x4 a = *(const f32x4*)(src + i);
  f32x4 b = *(const f32x4*)(src + i + 4);
  u16 o[8] __attribute__((aligned(16)));
#pragma unroll
  for (int j = 0; j < 4; ++j) { o[j] = f2bf(a[j]); o[4 + j] = f2bf(b[j]); }
  *(uint4*)(dst + i) = *(const uint4*)o;
}

// ---------------------------------------------------------------------------
// C = A(Mx1024) @ B^T(Nx1024) + bias.  BM=BN=128, BK=32, 256 thr = 4 waves 2x2.
// MODE 0: blockIdx.z selects (Wq,Wk,Wv); bf16 out in [b][h][s][dk] head layout.
// MODE 1: fp32 out to Fout[m*1024+n] (final projection).
// LDS pad +8 (stride 40 ushorts = 80B, 16B-aligned frag reads, 2-way banks = free)
// ---------------------------------------------------------------------------
template <int MODE>
__global__ __launch_bounds__(256) void gemm_bt(
    const u16* __restrict__ A,
    const u16* __restrict__ B0, const u16* __restrict__ B1, const u16* __restrict__ B2,
    const float* __restrict__ c0, const float* __restrict__ c1, const float* __restrict__ c2,
    u16* __restrict__ D0, u16* __restrict__ D1, u16* __restrict__ D2,
    float* __restrict__ Fout)
{
  constexpr int K = 1024;
  const u16* Bmat; const float* bias; u16* Dd = nullptr;
  if constexpr (MODE == 0) {
    int z = blockIdx.z;
    Bmat = (z == 0) ? B0 : (z == 1) ? B1 : B2;
    bias = (z == 0) ? c0 : (z == 1) ? c1 : c2;
    Dd   = (z == 0) ? D0 : (z == 1) ? D1 : D2;
  } else {
    Bmat = B0; bias = c0;
  }

  const int bm0 = blockIdx.x * 128;
  const int bn0 = blockIdx.y * 128;
  const int tid = threadIdx.x;
  const int wid = tid >> 6, lane = tid & 63, quad = lane >> 4, l16 = lane & 15;
  const int wm = (wid >> 1) * 64, wn = (wid & 1) * 64;

  __shared__ u16 As[128][40];
  __shared__ u16 Bs[128][40];

  f32x4 acc[4][4];
#pragma unroll
  for (int i = 0; i < 4; ++i)
#pragma unroll
    for (int j = 0; j < 4; ++j) acc[i][j] = {0.f, 0.f, 0.f, 0.f};

  // staging: 128 rows x 4 chunks(16B) per matrix; thread -> 2 rows each
  const int r0 = tid >> 2, cc = (tid & 3) * 8;
  const int r1 = r0 + 64;
  const u16* Ag = A    + (size_t)bm0 * K;
  const u16* Bg = Bmat + (size_t)bn0 * K;

  uint4 ra0 = *(const uint4*)(Ag + (size_t)r0 * K + cc);
  uint4 ra1 = *(const uint4*)(Ag + (size_t)r1 * K + cc);
  uint4 rb0 = *(const uint4*)(Bg + (size_t)r0 * K + cc);
  uint4 rb1 = *(const uint4*)(Bg + (size_t)r1 * K + cc);

  for (int kt = 0; kt < K / 32; ++kt) {
    __syncthreads();
    *(uint4*)&As[r0][cc] = ra0;
    *(uint4*)&As[r1][cc] = ra1;
    *(uint4*)&Bs[r0][cc] = rb0;
    *(uint4*)&Bs[r1][cc] = rb1;
    __syncthreads();
    if (kt + 1 < K / 32) {
      const int k0 = (kt + 1) * 32;
      ra0 = *(const uint4*)(Ag + (size_t)r0 * K + k0 + cc);
      ra1 = *(const uint4*)(Ag + (size_t)r1 * K + k0 + cc);
      rb0 = *(const uint4*)(Bg + (size_t)r0 * K + k0 + cc);
      rb1 = *(const uint4*)(Bg + (size_t)r1 * K + k0 + cc);
    }
    short8 af[4], bf[4];
#pragma unroll
    for (int t = 0; t < 4; ++t) {
      af[t] = *(const short8*)&As[wm + t * 16 + l16][quad * 8];
      bf[t] = *(const short8*)&Bs[wn + t * 16 + l16][quad * 8];
    }
#pragma unroll
    for (int i = 0; i < 4; ++i)
#pragma unroll
      for (int j = 0; j < 4; ++j)
        acc[i][j] = MFMA_BF16(af[i], bf[j], acc[i][j]);
  }

  // epilogue: C/D layout col=lane&15, row=quad*4+reg (verified m89/m91)
#pragma unroll
  for (int i = 0; i < 4; ++i) {
#pragma unroll
    for (int j = 0; j < 4; ++j) {
      const int gn = bn0 + wn + j * 16 + l16;
      const float bv = bias[gn];
#pragma unroll
      for (int r = 0; r < 4; ++r) {
        const int gm = bm0 + wm + i * 16 + quad * 4 + r;
        const float val = acc[i][j][r] + bv;
        if constexpr (MODE == 0) {
          const int bb = gm >> 11, s = gm & 2047, hh = gn >> 6, dk = gn & 63;
          Dd[(((size_t)(bb * 16 + hh) * 2048 + s) * 64) + dk] = f2bf(val);
        } else {
          Fout[(size_t)gm * 1024 + gn] = val;
        }
      }
    }
  }
}

// ---------------------------------------------------------------------------
// V [bh][s][dk] -> VT [bh][dk][s]  (so PV B-fragments are kpos-contiguous)
// ---------------------------------------------------------------------------
__global__ __launch_bounds__(256) void transpose_v(const u16* __restrict__ Vb,
                                                   u16* __restrict__ VbT) {
  const int st = blockIdx.x;   // s-tile (64 rows)
  const int bh = blockIdx.y;
  const int tid = threadIdx.x;
  __shared__ u16 T[64][72];
  const u16* src = Vb + ((size_t)bh * 2048 + st * 64) * 64;
  const int r0 = tid >> 3, c0 = (tid & 7) * 8;
  *(uint4*)&T[r0][c0]      = *(const uint4*)(src + (size_t)r0 * 64 + c0);
  *(uint4*)&T[r0 + 32][c0] = *(const uint4*)(src + (size_t)(r0 + 32) * 64 + c0);
  __syncthreads();
  u16* dst = VbT + (size_t)bh * 64 * 2048 + st * 64;
#pragma unroll
  for (int i = 0; i < 2; ++i) {
    const int dk = r0 + i * 32;
    u16 tmp[8] __attribute__((aligned(16)));
#pragma unroll
    for (int j = 0; j < 8; ++j) tmp[j] = T[c0 + j][dk];
    *(uint4*)(dst + (size_t)dk * 2048 + c0) = *(const uint4*)tmp;
  }
}

// ---------------------------------------------------------------------------
// Fused attention. Grid (32 q-tiles, 16 heads, 4 batch), 256 thr = 4 waves.
// Each wave owns 16 q-rows. Two passes over K (recompute scores in pass 2):
//  pass1: online (m,l);  pass2: P = exp(s-m)/l -> write attn fp32 + ctx += P@V.
// ---------------------------------------------------------------------------
__global__ __launch_bounds__(256) void attn_kernel(
    const u16* __restrict__ Qb, const u16* __restrict__ Kb, const u16* __restrict__ VbT,
    const int* __restrict__ mask, float* __restrict__ attn_out, u16* __restrict__ Ctx)
{
  const int qt = blockIdx.x;
  const int h  = blockIdx.y;
  const int b  = blockIdx.z;
  const int bh = b * 16 + h;
  const int tid = threadIdx.x;
  const int wid = tid >> 6, lane = tid & 63, quad = lane >> 4, l16 = lane & 15;

  __shared__ u16 Ks[64][72];        // [kpos][dk], pad->2-way banks
  __shared__ u16 Vs[64][72];        // [dk][kpos] (from VbT), pad->2-way banks
  __shared__ float Ps[4][16][68];   // per-wave P tile, pad->2-way banks

  const u16* Kbase = Kb  + (size_t)bh * 2048 * 64;
  const u16* Vbase = VbT + (size_t)bh * 64 * 2048;
  const u16* Qbase = Qb  + (size_t)bh * 2048 * 64;
  const int* mrow  = mask + b * 2048;

  const int q0 = qt * 64 + wid * 16;

  // Q A-fragments (A[m=lane&15][k=quad*8+j]), DK=64 -> 2 K-steps
  short8 qf0 = *(const short8*)(Qbase + (size_t)(q0 + l16) * 64 + quad * 8);
  short8 qf1 = *(const short8*)(Qbase + (size_t)(q0 + l16) * 64 + 32 + quad * 8);

  float m_r[4], l_r[4];
#pragma unroll
  for (int r = 0; r < 4; ++r) { m_r[r] = -1e30f; l_r[r] = 0.f; }

  const int sr0 = tid >> 3, sc = (tid & 7) * 8;
  const int sr1 = sr0 + 32;

  // ---------------- pass 1: row max + sumexp (online) ----------------
  for (int kt = 0; kt < 32; ++kt) {
    __syncthreads();
    *(uint4*)&Ks[sr0][sc] = *(const uint4*)(Kbase + (size_t)(kt * 64 + sr0) * 64 + sc);
    *(uint4*)&Ks[sr1][sc] = *(const uint4*)(Kbase + (size_t)(kt * 64 + sr1) * 64 + sc);
    __syncthreads();

    float scv[4][4];
#pragma unroll
    for (int ct = 0; ct < 4; ++ct) {
      short8 kf0 = *(const short8*)&Ks[ct * 16 + l16][quad * 8];
      short8 kf1 = *(const short8*)&Ks[ct * 16 + l16][32 + quad * 8];
      f32x4 a = {0.f, 0.f, 0.f, 0.f};
      a = MFMA_BF16(qf0, kf0, a);
      a = MFMA_BF16(qf1, kf1, a);
      const int kp = kt * 64 + ct * 16 + l16;
      const bool valid = (mrow[kp] != 0);
#pragma unroll
      for (int r = 0; r < 4; ++r) scv[ct][r] = valid ? a[r] * 0.125f : -1e30f;
    }
#pragma unroll
    for (int r = 0; r < 4; ++r) {
      float tmax = fmaxf(fmaxf(scv[0][r], scv[1][r]), fmaxf(scv[2][r], scv[3][r]));
#pragma unroll
      for (int off = 1; off < 16; off <<= 1) tmax = fmaxf(tmax, __shfl_xor(tmax, off, 16));
      const float mnew = fmaxf(m_r[r], tmax);
      float ts = __expf(scv[0][r] - mnew) + __expf(scv[1][r] - mnew) +
                 __expf(scv[2][r] - mnew) + __expf(scv[3][r] - mnew);
#pragma unroll
      for (int off = 1; off < 16; off <<= 1) ts += __shfl_xor(ts, off, 16);
      l_r[r] = l_r[r] * __expf(m_r[r] - mnew) + ts;
      m_r[r] = mnew;
    }
  }
  float inv_l[4];
#pragma unroll
  for (int r = 0; r < 4; ++r) inv_l[r] = 1.f / l_r[r];

  // ---------------- pass 2: write attn + accumulate ctx ----------------
  f32x4 cacc[4];
#pragma unroll
  for (int ct = 0; ct < 4; ++ct) cacc[ct] = {0.f, 0.f, 0.f, 0.f};

  for (int kt = 0; kt < 32; ++kt) {
    __syncthreads();
    *(uint4*)&Ks[sr0][sc] = *(const uint4*)(Kbase + (size_t)(kt * 64 + sr0) * 64 + sc);
    *(uint4*)&Ks[sr1][sc] = *(const uint4*)(Kbase + (size_t)(kt * 64 + sr1) * 64 + sc);
    *(uint4*)&Vs[sr0][sc] = *(const uint4*)(Vbase + (size_t)sr0 * 2048 + kt * 64 + sc);
    *(uint4*)&Vs[sr1][sc] = *(const uint4*)(Vbase + (size_t)sr1 * 2048 + kt * 64 + sc);
    __syncthreads();

    // recompute scores (bitwise identical to pass 1), normalize, park in LDS
#pragma unroll
    for (int ct = 0; ct < 4; ++ct) {
      short8 kf0 = *(const short8*)&Ks[ct * 16 + l16][quad * 8];
      short8 kf1 = *(const short8*)&Ks[ct * 16 + l16][32 + quad * 8];
      f32x4 a = {0.f, 0.f, 0.f, 0.f};
      a = MFMA_BF16(qf0, kf0, a);
      a = MFMA_BF16(qf1, kf1, a);
      const int kp = kt * 64 + ct * 16 + l16;
      const bool valid = (mrow[kp] != 0);
#pragma unroll
      for (int r = 0; r < 4; ++r) {
        const float s = valid ? a[r] * 0.125f : -1e30f;
        Ps[wid][quad * 4 + r][ct * 16 + l16] = __expf(s - m_r[r]) * inv_l[r];
      }
    }
    __syncthreads();

    // attn tile store: 16x64 fp32 via float4 (256B/quad coalesced)
#pragma unroll
    for (int it = 0; it < 4; ++it) {
      const int row = it * 4 + quad;
      f32x4 pv = *(const f32x4*)&Ps[wid][row][l16 * 4];
      const size_t off = ((size_t)bh * 2048 + (q0 + row)) * 2048 + (size_t)kt * 64 + l16 * 4;
      *(f32x4*)(attn_out + off) = pv;
    }

    // PV: P via LDS round-trip into A-layout, V from Vs (B-layout, b128 reads)
#pragma unroll
    for (int s = 0; s < 2; ++s) {
      f32x4 p0 = *(const f32x4*)&Ps[wid][l16][s * 32 + quad * 8];
      f32x4 p1 = *(const f32x4*)&Ps[wid][l16][s * 32 + quad * 8 + 4];
      short8 af;
#pragma unroll
      for (int j = 0; j < 4; ++j) {
        af[j]     = (short)f2bf(p0[j]);
        af[4 + j] = (short)f2bf(p1[j]);
      }
#pragma unroll
      for (int ct = 0; ct < 4; ++ct) {
        short8 vf = *(const short8*)&Vs[ct * 16 + l16][s * 32 + quad * 8];
        cacc[ct] = MFMA_BF16(af, vf, cacc[ct]);
      }
    }
  }

  // ctx epilogue -> [b][s][h*64+dk] bf16 (A-matrix layout for final GEMM)
#pragma unroll
  for (int ct = 0; ct < 4; ++ct) {
#pragma unroll
    for (int r = 0; r < 4; ++r) {
      const int srow = q0 + quad * 4 + r;
      Ctx[((size_t)(b * 2048 + srow)) * 1024 + h * 64 + ct * 16 + l16] = f2bf(cacc[ct][r]);
    }
  }
}

// ---------------------------------------------------------------------------
extern "C" void kernel_launch(void* const* d_in, const int* in_sizes, int n_in,
                              void* d_out, int out_size, void* d_ws, size_t ws_size,
                              hipStream_t stream) {
  const float* hidden = (const float*)d_in[0];
  const int*   amask  = (const int*)d_in[1];
  const float* Wq = (const float*)d_in[2];
  const float* bq = (const float*)d_in[3];
  const float* Wk = (const float*)d_in[4];
  const float* bk = (const float*)d_in[5];
  const float* Wv = (const float*)d_in[6];
  const float* bv = (const float*)d_in[7];
  const float* Wo = (const float*)d_in[8];
  const float* bo = (const float*)d_in[9];

  float* out  = (float*)d_out;
  float* attn = out + (size_t)4 * 2048 * 1024;   // out first, then attn

  // workspace layout (bytes): needs ~104 MiB
  char* ws = (char*)d_ws;
  u16* Xb  = (u16*)(ws + 0);          // 16 MiB  X bf16 [8192][1024]
  u16* Wqb = (u16*)(ws + 16777216);   // 2 MiB
  u16* Wkb = (u16*)(ws + 18874368);
  u16* Wvb = (u16*)(ws + 20971520);
  u16* Wob = (u16*)(ws + 23068672);
  u16* Qb  = (u16*)(ws + 25165824);   // 16 MiB  [b][h][s][dk]
  u16* Kb  = (u16*)(ws + 41943040);   // 16 MiB  [b][h][s][dk]
  u16* Vb  = (u16*)(ws + 58720256);   // 16 MiB  [b][h][s][dk]
  u16* Ctx = (u16*)(ws + 75497472);   // 16 MiB  [b*s][1024]
  u16* VbT = (u16*)(ws + 92274688);   // 16 MiB  [b][h][dk][s]

  cvt_f32_bf16<<<dim3(4096), dim3(256), 0, stream>>>(hidden, Xb, 8388608);
  cvt_f32_bf16<<<dim3(512),  dim3(256), 0, stream>>>(Wq, Wqb, 1048576);
  cvt_f32_bf16<<<dim3(512),  dim3(256), 0, stream>>>(Wk, Wkb, 1048576);
  cvt_f32_bf16<<<dim3(512),  dim3(256), 0, stream>>>(Wv, Wvb, 1048576);
  cvt_f32_bf16<<<dim3(512),  dim3(256), 0, stream>>>(Wo, Wob, 1048576);

  gemm_bt<0><<<dim3(64, 8, 3), dim3(256), 0, stream>>>(
      Xb, Wqb, Wkb, Wvb, bq, bk, bv, Qb, Kb, Vb, nullptr);

  transpose_v<<<dim3(32, 64), dim3(256), 0, stream>>>(Vb, VbT);

  attn_kernel<<<dim3(32, 16, 4), dim3(256), 0, stream>>>(Qb, Kb, VbT, amask, attn, Ctx);

  gemm_bt<1><<<dim3(64, 8, 1), dim3(256), 0, stream>>>(
      Ctx, Wob, nullptr, nullptr, bo, nullptr, nullptr,
      nullptr, nullptr, nullptr, out);
}